// Round 1
// baseline (11670.934 us; speedup 1.0000x reference)
//
#include <hip/hip_runtime.h>
#include <math.h>

#define Bq 32
#define Sq 512
#define Tq 32
#define EMBq 256
#define HIDq 512
#define VOCABq 50000
#define OOVq 100
#define VEXTq (VOCABq + OOVq)

__device__ __forceinline__ float sigmoidf_(float x){ return 1.0f/(1.0f+__expf(-x)); }

// ---- block-wide reductions, 512 threads = 8 waves ----
__device__ __forceinline__ float blockSum512(float v, float* red){
  #pragma unroll
  for (int off=32; off>0; off>>=1) v += __shfl_down(v, off);
  int lane = threadIdx.x & 63, wid = threadIdx.x >> 6;
  __syncthreads();                 // protect red from previous use
  if (lane==0) red[wid]=v;
  __syncthreads();
  float t=0.f;
  #pragma unroll
  for (int w=0;w<8;++w) t+=red[w];
  return t;
}
__device__ __forceinline__ float blockMax512(float v, float* red){
  #pragma unroll
  for (int off=32; off>0; off>>=1) v = fmaxf(v, __shfl_down(v, off));
  int lane = threadIdx.x & 63, wid = threadIdx.x >> 6;
  __syncthreads();
  if (lane==0) red[wid]=v;
  __syncthreads();
  float t=red[0];
  #pragma unroll
  for (int w=1;w<8;++w) t=fmaxf(t,red[w]);
  return t;
}

// ---- enc_feat = encoder_states @ W_enc + b_enc   [B*S,512]x[512,512] ----
__global__ __launch_bounds__(512) void k_enc(const float* __restrict__ es,
    const float* __restrict__ W_enc, const float* __restrict__ b_enc,
    float* __restrict__ ef){
  __shared__ float A[16][256];
  const int tid = threadIdx.x;
  const int r0  = blockIdx.x * 16;
  float acc[16];
  #pragma unroll
  for (int r=0;r<16;++r) acc[r]=0.f;
  for (int kc=0;kc<2;++kc){
    __syncthreads();
    for (int i=tid;i<16*256;i+=512){
      int rr=i>>8, kk=i&255;
      A[rr][kk]=es[(size_t)(r0+rr)*HIDq + kc*256 + kk];
    }
    __syncthreads();
    for (int k=0;k<256;++k){
      float w=W_enc[(size_t)(kc*256+k)*HIDq + tid];
      #pragma unroll
      for (int r=0;r<16;++r) acc[r]+=A[r][k]*w;
    }
  }
  float bb=b_enc[tid];
  #pragma unroll
  for (int r=0;r<16;++r) ef[(size_t)(r0+r)*HIDq+tid]=acc[r]+bb;
}

// ---- recurrent decoder: one block per batch element ----
__global__ __launch_bounds__(512) void k_rec(
  const int*   __restrict__ dec_ids,    // [B,T]
  const float* __restrict__ embeddings, // [VOCAB,EMB]
  const float* __restrict__ enc_feat,   // [B,S,HID]
  const float* __restrict__ mask,       // [B,S]
  const float* __restrict__ init_h, const float* __restrict__ init_c,
  const float* __restrict__ W_attn,     // [2H,H]
  const float* __restrict__ vvec, const float* __restrict__ w_cov,
  const float* __restrict__ b_cov,
  const float* __restrict__ W_x,        // [EMB+H,H]
  const float* __restrict__ Wk, const float* __restrict__ Wr, // [H,4H]
  const float* __restrict__ b_lstm,     // [4H]
  const float* __restrict__ W_pgen,     // [4H]
  float* __restrict__ attn_out,         // [T,B,S]
  float* __restrict__ hc_out,           // [T,B,1024] = [h,ctx]
  float* __restrict__ pgen_out)         // [T,B]
{
  __shared__ float h[HIDq], c[HIDq], ctx[HIDq], x[HIDq], df[HIDq];
  __shared__ float attn[Sq], cov[Sq];
  __shared__ float vl[HIDq], wcl[HIDq], bcl[HIDq];
  __shared__ float red[8];
  const int b = blockIdx.x, tid = threadIdx.x;
  h[tid]=init_h[b*HIDq+tid]; c[tid]=init_c[b*HIDq+tid]; ctx[tid]=0.f;
  vl[tid]=vvec[tid]; wcl[tid]=w_cov[tid]; bcl[tid]=b_cov[tid];
  const float mk = mask[b*Sq+tid];
  const float* efb = enc_feat + (size_t)b*Sq*HIDq;
  __syncthreads();

  for (int t=0;t<Tq;++t){
    // ---- x = [emb_t ; ctx] @ W_x ----
    const float* erow = embeddings + (size_t)dec_ids[b*Tq+t]*EMBq;
    float xa = 0.f;
    for (int k=0;k<EMBq;++k) xa += erow[k]*W_x[k*HIDq+tid];
    for (int k=0;k<HIDq;++k) xa += ctx[k]*W_x[(EMBq+k)*HIDq+tid];
    x[tid]=xa;
    __syncthreads();

    // ---- z = x@Wk + h@Wr + b; gates ----
    float zi=b_lstm[tid], zf=b_lstm[HIDq+tid], zg=b_lstm[2*HIDq+tid], zo=b_lstm[3*HIDq+tid];
    for (int k=0;k<HIDq;++k){
      float xv=x[k], hv=h[k];
      const float* wk = Wk + (size_t)k*4*HIDq;
      const float* wr = Wr + (size_t)k*4*HIDq;
      zi += xv*wk[tid]        + hv*wr[tid];
      zf += xv*wk[HIDq+tid]   + hv*wr[HIDq+tid];
      zg += xv*wk[2*HIDq+tid] + hv*wr[2*HIDq+tid];
      zo += xv*wk[3*HIDq+tid] + hv*wr[3*HIDq+tid];
    }
    float cn = sigmoidf_(zf)*c[tid] + sigmoidf_(zi)*tanhf(zg);
    float hn = sigmoidf_(zo)*tanhf(cn);
    __syncthreads();            // everyone done reading old h,c
    h[tid]=hn; c[tid]=cn;
    __syncthreads();

    // ---- dec_feat = [h;c] @ W_attn ----
    float dfa=0.f;
    for (int k=0;k<HIDq;++k)
      dfa += h[k]*W_attn[k*HIDq+tid] + c[k]*W_attn[(HIDq+k)*HIDq+tid];
    df[tid]=dfa;
    __syncthreads();

    // ---- e[s] for s = tid ----
    const float* efr = efb + (size_t)tid*HIDq;
    float e=0.f;
    if (t==0){
      for (int j=0;j<HIDq;++j) e += vl[j]*tanhf(efr[j]+df[j]);
    } else {
      float cv = cov[tid];
      for (int j=0;j<HIDq;++j) e += vl[j]*tanhf(efr[j]+df[j]+cv*wcl[j]+bcl[j]);
    }

    // ---- masked softmax over s ----
    float m  = blockMax512(e, red);
    float ex = __expf(e-m);
    float s1 = blockSum512(ex, red);
    float a  = (ex/s1)*mk;
    float s2 = blockSum512(a, red);
    a = a/s2;
    attn[tid]=a;
    attn_out[((size_t)t*Bq+b)*Sq+tid]=a;
    cov[tid] = (t==0)? a : (cov[tid]+a);
    __syncthreads();

    // ---- ctx[j] = sum_s attn[s] * enc_feat[b,s,j], j = tid ----
    float cx=0.f;
    for (int s=0;s<Sq;++s) cx += attn[s]*efb[(size_t)s*HIDq+tid];
    ctx[tid]=cx;
    __syncthreads();

    // ---- p_gen = sigmoid([ctx,h,c,x] @ W_pgen) ----
    float pp = cx*W_pgen[tid] + hn*W_pgen[HIDq+tid]
             + cn*W_pgen[2*HIDq+tid] + xa*W_pgen[3*HIDq+tid];
    float ptot = blockSum512(pp, red);
    if (tid==0) pgen_out[t*Bq+b] = sigmoidf_(ptot);

    // ---- store [h, ctx] for deferred output projection ----
    size_t ro = ((size_t)t*Bq+b)*1024;
    hc_out[ro+tid]=hn; hc_out[ro+HIDq+tid]=cx;
    __syncthreads();
  }
}

// ---- OUTm = [h,ctx] @ W_out   [1024,1024]x[1024,512] ----
__global__ __launch_bounds__(512) void k_mid(const float* __restrict__ hc,
    const float* __restrict__ W_out, float* __restrict__ outm){
  __shared__ float A[16][256];
  const int tid=threadIdx.x;
  const int r0=blockIdx.x*16;
  float acc[16];
  #pragma unroll
  for (int r=0;r<16;++r) acc[r]=0.f;
  for (int kc=0;kc<4;++kc){
    __syncthreads();
    for (int i=tid;i<16*256;i+=512){
      int rr=i>>8, kk=i&255;
      A[rr][kk]=hc[(size_t)(r0+rr)*1024 + kc*256+kk];
    }
    __syncthreads();
    for (int k=0;k<256;++k){
      float w=W_out[(size_t)(kc*256+k)*HIDq + tid];
      #pragma unroll
      for (int r=0;r<16;++r) acc[r]+=A[r][k]*w;
    }
  }
  #pragma unroll
  for (int r=0;r<16;++r) outm[(size_t)(r0+r)*HIDq+tid]=acc[r];
}

// ---- logits = OUTm @ W_proj + b_proj  -> staged into d_out rows ----
// M=1024, N=50000, K=512.  Mtile=64 (K chunked by 128 to fit 32KB LDS), Ntile=512.
__global__ __launch_bounds__(512) void k_proj(const float* __restrict__ outm,
    const float* __restrict__ W_proj, const float* __restrict__ b_proj,
    float* __restrict__ out){
  __shared__ float A[64][128];
  const int tid = threadIdx.x;
  const int r0  = blockIdx.y * 64;
  const int n   = blockIdx.x * 512 + tid;
  const bool ok = (n < VOCABq);
  float acc[64];
  #pragma unroll
  for (int r=0;r<64;++r) acc[r]=0.f;
  for (int kc=0;kc<4;++kc){
    __syncthreads();
    for (int i=tid;i<64*128;i+=512){
      int rr=i>>7, kk=i&127;
      A[rr][kk]=outm[(size_t)(r0+rr)*HIDq + kc*128 + kk];
    }
    __syncthreads();
    if (ok){
      const float* wp = W_proj + (size_t)(kc*128)*VOCABq + n;
      for (int k=0;k<128;++k){
        float w = wp[(size_t)k*VOCABq];
        #pragma unroll
        for (int r=0;r<64;++r) acc[r] += A[r][k]*w;
      }
    }
  }
  if (ok){
    float bp = b_proj[n];
    #pragma unroll
    for (int r=0;r<64;++r) out[(size_t)(r0+r)*VEXTq + n] = acc[r]+bp;
  }
}

// ---- per-row softmax * p_gen, zero OOV, scatter-add (1-pg)*attn ----
__global__ __launch_bounds__(256) void k_sm(float* __restrict__ out,
    const float* __restrict__ pgen, const float* __restrict__ attn_ws,
    const int* __restrict__ enc_ids){
  __shared__ float redm[4], reds[4];
  const int row=blockIdx.x, tid=threadIdx.x;
  const int b = row & (Bq-1);
  float* orow = out + (size_t)row*VEXTq;
  // online max+sum over the logits we staged in d_out
  float m=-1e30f, s=0.f;
  for (int i=tid;i<VOCABq;i+=256){
    float l=orow[i];
    float nm=fmaxf(m,l);
    s = s*__expf(m-nm) + __expf(l-nm);
    m = nm;
  }
  #pragma unroll
  for (int off=32; off>0; off>>=1){
    float om=__shfl_down(m,off), os=__shfl_down(s,off);
    float nm=fmaxf(m,om);
    s = s*__expf(m-nm)+os*__expf(om-nm);
    m = nm;
  }
  int lane=tid&63, wid=tid>>6;
  if (lane==0){ redm[wid]=m; reds[wid]=s; }
  __syncthreads();
  float M=redm[0];
  #pragma unroll
  for (int w=1;w<4;++w) M=fmaxf(M,redm[w]);
  float Ssum=0.f;
  #pragma unroll
  for (int w=0;w<4;++w) Ssum += reds[w]*__expf(redm[w]-M);
  const float pg = pgen[row];
  const float scale = pg/Ssum;
  for (int i=tid;i<VOCABq;i+=256) orow[i]=scale*__expf(orow[i]-M);
  for (int i=VOCABq+tid;i<VEXTq;i+=256) orow[i]=0.f;
  __syncthreads();
  const float w1 = 1.f-pg;
  const float* arow = attn_ws + (size_t)row*Sq;
  const int* ids = enc_ids + b*Sq;
  for (int si=tid; si<Sq; si+=256)
    atomicAdd(&orow[ids[si]], w1*arow[si]);
}

extern "C" void kernel_launch(void* const* d_in, const int* in_sizes, int n_in,
                              void* d_out, int out_size, void* d_ws, size_t ws_size,
                              hipStream_t stream) {
  (void)in_sizes; (void)n_in; (void)out_size; (void)ws_size;
  const int*   dec_ids    = (const int*)  d_in[0];
  const int*   enc_ids    = (const int*)  d_in[1];
  const float* enc_states = (const float*)d_in[2];
  const float* mask       = (const float*)d_in[3];
  const float* init_h     = (const float*)d_in[4];
  const float* init_c     = (const float*)d_in[5];
  const float* embeddings = (const float*)d_in[6];
  const float* W_enc      = (const float*)d_in[7];
  const float* b_enc      = (const float*)d_in[8];
  const float* W_attn     = (const float*)d_in[9];
  const float* vvec       = (const float*)d_in[10];
  const float* w_cov      = (const float*)d_in[11];
  const float* b_cov      = (const float*)d_in[12];
  const float* W_x        = (const float*)d_in[13];
  const float* W_out      = (const float*)d_in[14];
  const float* Wk         = (const float*)d_in[15];
  const float* Wr         = (const float*)d_in[16];
  const float* b_lstm     = (const float*)d_in[17];
  const float* W_pgen     = (const float*)d_in[18];
  const float* W_proj     = (const float*)d_in[19];
  const float* b_proj     = (const float*)d_in[20];
  float* out = (float*)d_out;
  float* ws  = (float*)d_ws;

  float* enc_feat = ws;                                   // 32*512*512   = 8,388,608
  float* attn_ws  = enc_feat + (size_t)Bq*Sq*HIDq;        // 32*32*512    =   524,288
  float* hc_ws    = attn_ws  + (size_t)Tq*Bq*Sq;          // 1024*1024    = 1,048,576
  float* outm_ws  = hc_ws    + (size_t)Tq*Bq*1024;        // 1024*512     =   524,288
  float* pgen_ws  = outm_ws  + (size_t)Tq*Bq*HIDq;        // 1024
  // total ws: ~10.49M floats = ~42 MB

  k_enc<<<(Bq*Sq)/16, 512, 0, stream>>>(enc_states, W_enc, b_enc, enc_feat);
  k_rec<<<Bq, 512, 0, stream>>>(dec_ids, embeddings, enc_feat, mask, init_h, init_c,
                                W_attn, vvec, w_cov, b_cov, W_x, Wk, Wr, b_lstm,
                                W_pgen, attn_ws, hc_ws, pgen_ws);
  k_mid<<<(Tq*Bq)/16, 512, 0, stream>>>(hc_ws, W_out, outm_ws);
  dim3 gp(98, 16);
  k_proj<<<gp, 512, 0, stream>>>(outm_ws, W_proj, b_proj, out);
  k_sm<<<Tq*Bq, 256, 0, stream>>>(out, pgen_ws, attn_ws, enc_ids);
}

// Round 2
// 7097.515 us; speedup vs baseline: 1.6444x; 1.6444x over previous
//
#include <hip/hip_runtime.h>
#include <math.h>

#define Bq 32
#define Sq 512
#define Tq 32
#define EMBq 256
#define HIDq 512
#define VOCABq 50000
#define OOVq 100
#define VEXTq (VOCABq + OOVq)

__device__ __forceinline__ float sigmoidf_(float x){ return 1.0f/(1.0f+__expf(-x)); }

__device__ __forceinline__ float blockSum512(float v, float* red){
  #pragma unroll
  for (int off=32; off>0; off>>=1) v += __shfl_down(v, off);
  int lane = threadIdx.x & 63, wid = threadIdx.x >> 6;
  __syncthreads();
  if (lane==0) red[wid]=v;
  __syncthreads();
  float t=0.f;
  #pragma unroll
  for (int w=0;w<8;++w) t+=red[w];
  return t;
}

// ---- enc_feat = encoder_states @ W_enc + b_enc ----
__global__ __launch_bounds__(512) void k_enc(const float* __restrict__ es,
    const float* __restrict__ W_enc, const float* __restrict__ b_enc,
    float* __restrict__ ef){
  __shared__ float A[16][256];
  const int tid = threadIdx.x;
  const int r0  = blockIdx.x * 16;
  float acc[16];
  #pragma unroll
  for (int r=0;r<16;++r) acc[r]=0.f;
  for (int kc=0;kc<2;++kc){
    __syncthreads();
    for (int i=tid;i<16*256;i+=512){
      int rr=i>>8, kk=i&255;
      A[rr][kk]=es[(size_t)(r0+rr)*HIDq + kc*256 + kk];
    }
    __syncthreads();
    for (int k=0;k<256;++k){
      float w=W_enc[(size_t)(kc*256+k)*HIDq + tid];
      #pragma unroll
      for (int r=0;r<16;++r) acc[r]+=A[r][k]*w;
    }
  }
  float bb=b_enc[tid];
  #pragma unroll
  for (int r=0;r<16;++r) ef[(size_t)(r0+r)*HIDq+tid]=acc[r]+bb;
}

// ---- embx[t*32+b,:] = emb(dec_ids[b,t]) @ W_x[0:256,:]; embxp = embx . Wp4 ----
__global__ __launch_bounds__(512) void k_embx(const int* __restrict__ dec_ids,
  const float* __restrict__ emb, const float* __restrict__ W_x,
  const float* __restrict__ Wpgen, float* __restrict__ embx, float* __restrict__ embxp){
  __shared__ float A[16][257];
  __shared__ int ids[16];
  __shared__ float red[8];
  const int tid = threadIdx.x, r0 = blockIdx.x*16;
  if (tid<16){
    int row = r0+tid, tt = row>>5, bb = row&31;
    ids[tid] = dec_ids[bb*Tq + tt];
  }
  __syncthreads();
  for (int idx=tid; idx<16*256; idx+=512){
    int rr = idx>>8, kk = idx&255;
    A[rr][kk] = emb[(size_t)ids[rr]*EMBq + kk];
  }
  __syncthreads();
  float acc[16];
  #pragma unroll
  for (int r=0;r<16;++r) acc[r]=0.f;
  for (int k=0;k<256;++k){
    float w = W_x[(size_t)k*HIDq + tid];
    #pragma unroll
    for (int r=0;r<16;++r) acc[r] += A[r][k]*w;
  }
  float wp4 = Wpgen[1536+tid];
  for (int r=0;r<16;++r){
    embx[(size_t)(r0+r)*HIDq + tid] = acc[r];
    float s = blockSum512(acc[r]*wp4, red);
    if (tid==0) embxp[r0+r] = s;
  }
}

// ---- embz = embx @ Wk + b_lstm   [1024,512]x[512,2048] ----
__global__ __launch_bounds__(512) void k_embz(const float* __restrict__ embx,
  const float* __restrict__ Wk, const float* __restrict__ b_lstm, float* __restrict__ embz){
  __shared__ float A[16][513];
  const int tid = threadIdx.x;
  const int r0 = blockIdx.x*16;
  const int n  = blockIdx.y*512 + tid;
  for (int idx=tid; idx<16*512; idx+=512){
    int rr=idx>>9, kk=idx&511;
    A[rr][kk] = embx[(size_t)(r0+rr)*HIDq + kk];
  }
  __syncthreads();
  float acc[16];
  #pragma unroll
  for (int r=0;r<16;++r) acc[r]=0.f;
  for (int k=0;k<512;++k){
    float w = Wk[(size_t)k*2048 + n];
    #pragma unroll
    for (int r=0;r<16;++r) acc[r] += A[r][k]*w;
  }
  float bl = b_lstm[n];
  #pragma unroll
  for (int r=0;r<16;++r) embz[(size_t)(r0+r)*2048 + n] = acc[r]+bl;
}

// ---- WXKT[n][j] = sum_i Wk[i][n] * W_x[256+j][i] ----
__global__ __launch_bounds__(512) void k_wxk(const float* __restrict__ Wk,
    const float* __restrict__ W_x, float* __restrict__ WXKT_){
  __shared__ float KT[32][64];
  __shared__ float X2[32][33];
  const int tid = threadIdx.x;
  const int n0 = blockIdx.x * 64;
  const int j0 = blockIdx.y * 32;
  const int jj = tid & 31;
  const int ng = tid >> 5;   // 0..15
  float acc[4] = {0,0,0,0};
  for (int i0=0;i0<512;i0+=32){
    __syncthreads();
    for (int idx=tid; idx<32*64; idx+=512){
      int ii = idx>>6, nn = idx&63;
      KT[ii][nn] = Wk[(size_t)(i0+ii)*2048 + n0+nn];
    }
    for (int idx=tid; idx<32*32; idx+=512){
      int j2 = idx>>5, i2 = idx&31;
      X2[j2][i2] = W_x[(size_t)(256+j0+j2)*HIDq + i0+i2];
    }
    __syncthreads();
    for (int ii=0;ii<32;++ii){
      float xv = X2[jj][ii];
      #pragma unroll
      for (int q=0;q<4;++q) acc[q] += KT[ii][ng*4+q]*xv;
    }
  }
  #pragma unroll
  for (int q=0;q<4;++q) WXKT_[(size_t)(n0+ng*4+q)*512 + j0+jj] = acc[q];
}

// ---- generic 32x32 tiled transpose: out[n][k] = in[k][n], in is [K][N] ----
__global__ __launch_bounds__(512) void k_trans(const float* __restrict__ in,
    float* __restrict__ out, int K, int N){
  __shared__ float T[32][33];
  const int n0 = blockIdx.x*32, k0 = blockIdx.y*32;
  const int tid = threadIdx.x;
  for (int idx=tid; idx<1024; idx+=512){
    int kk = idx>>5, nn = idx&31;
    T[kk][nn] = in[(size_t)(k0+kk)*N + n0+nn];
  }
  __syncthreads();
  for (int idx=tid; idx<1024; idx+=512){
    int nn = idx>>5, kk = idx&31;
    out[(size_t)(n0+nn)*K + k0+kk] = T[kk][nn];
  }
}

// ---- Wp1p[j] = W_pgen[j] + sum_i W_x[256+j][i]*W_pgen[1536+i] ----
__global__ __launch_bounds__(512) void k_wp(const float* __restrict__ W_x,
  const float* __restrict__ Wpgen, float* __restrict__ Wp1p){
  int j = threadIdx.x;
  const float* row = W_x + (size_t)(256+j)*HIDq;
  float s=0.f;
  for (int i=0;i<512;++i) s += row[i]*Wpgen[1536+i];
  Wp1p[j] = Wpgen[j] + s;
}

// ---- per-step LSTM kernel: finalize ctx(t-1) + z + gates. 32 blocks x 512 ----
__global__ __launch_bounds__(512) void kB(
  const float* __restrict__ h_src, int h_stride,
  const float* __restrict__ c_src, float* __restrict__ c_dst,
  const float* __restrict__ WXKT_, const float* __restrict__ WrT_,
  const float* __restrict__ embz, const float* __restrict__ embxp,
  const float* __restrict__ Wp1p, const float* __restrict__ Wpgen,
  const float* __restrict__ cp, const float* __restrict__ mZ,
  const float* __restrict__ e_rows, const float* __restrict__ mask,
  float* __restrict__ hc_ws, float* __restrict__ attn_ws,
  float* __restrict__ cov, float* __restrict__ pgen_ws,
  int t, int doMain)
{
  __shared__ float Actx[32][516];
  __shared__ float Ah[32][516];
  __shared__ float Mb[32], Db[32], Wl[32][8];
  __shared__ float red[8];
  const int tid = threadIdx.x, bid = blockIdx.x;

  for (int idx = tid; idx < 32*512; idx += 512){
    int b = idx >> 9, k = idx & 511;
    Ah[b][k] = h_src[(size_t)b*h_stride + k];
  }
  if (t == 0){
    for (int idx = tid; idx < 32*512; idx += 512){
      int b=idx>>9,k=idx&511; Actx[b][k]=0.f;
    }
    __syncthreads();
  } else {
    if (tid < 32){
      int b = tid;
      float m = mZ[(b*8+0)*2];
      #pragma unroll
      for (int l=1;l<8;++l) m = fmaxf(m, mZ[(b*8+l)*2]);
      float den = 0.f;
      #pragma unroll
      for (int l=0;l<8;++l){
        float w = __expf(mZ[(b*8+l)*2] - m);
        Wl[b][l] = w;
        den += w * mZ[(b*8+l)*2+1];
      }
      Mb[b] = m; Db[b] = den;
    }
    __syncthreads();
    for (int b=0;b<32;++b){
      float s = 0.f;
      #pragma unroll
      for (int l=0;l<8;++l) s += cp[((size_t)(b*8+l))*512 + tid] * Wl[b][l];
      Actx[b][tid] = s / Db[b];
    }
    __syncthreads();
    {
      const int b = bid;
      const float M = Mb[b], den = Db[b];
      float a = mask[b*512+tid] * __expf(e_rows[b*512+tid] - M) / den;
      attn_ws[((size_t)(t-1)*Bq + b)*Sq + tid] = a;
      cov[b*512+tid] = (t==1) ? a : (cov[b*512+tid] + a);
      hc_ws[((size_t)(t-1)*Bq + b)*1024 + 512 + tid] = Actx[b][tid];
      float val = Actx[b][tid]*Wp1p[tid] + Ah[b][tid]*Wpgen[512+tid]
                + c_src[b*512+tid]*Wpgen[1024+tid];
      float tot = blockSum512(val, red);
      if (tid==0) pgen_ws[(t-1)*Bq + b] = sigmoidf_(tot + embxp[(t-1)*Bq + b]);
    }
    __syncthreads();
  }

  if (doMain){
    const int j = tid >> 5;
    const int b = tid & 31;
    const int colj = bid*16 + j;
    const float* w0 = WXKT_ + (size_t)colj*512;
    const float* w1 = WXKT_ + (size_t)(512+colj)*512;
    const float* w2 = WXKT_ + (size_t)(1024+colj)*512;
    const float* w3 = WXKT_ + (size_t)(1536+colj)*512;
    float ai=0.f, af=0.f, ag=0.f, ao=0.f;
    for (int k=0;k<512;k+=4){
      float4 cx = *(const float4*)&Actx[b][k];
      float4 q0 = *(const float4*)(w0+k);
      float4 q1 = *(const float4*)(w1+k);
      float4 q2 = *(const float4*)(w2+k);
      float4 q3 = *(const float4*)(w3+k);
      ai += cx.x*q0.x + cx.y*q0.y + cx.z*q0.z + cx.w*q0.w;
      af += cx.x*q1.x + cx.y*q1.y + cx.z*q1.z + cx.w*q1.w;
      ag += cx.x*q2.x + cx.y*q2.y + cx.z*q2.z + cx.w*q2.w;
      ao += cx.x*q3.x + cx.y*q3.y + cx.z*q3.z + cx.w*q3.w;
    }
    const float* r0p = WrT_ + (size_t)colj*512;
    const float* r1p = WrT_ + (size_t)(512+colj)*512;
    const float* r2p = WrT_ + (size_t)(1024+colj)*512;
    const float* r3p = WrT_ + (size_t)(1536+colj)*512;
    for (int k=0;k<512;k+=4){
      float4 hx = *(const float4*)&Ah[b][k];
      float4 q0 = *(const float4*)(r0p+k);
      float4 q1 = *(const float4*)(r1p+k);
      float4 q2 = *(const float4*)(r2p+k);
      float4 q3 = *(const float4*)(r3p+k);
      ai += hx.x*q0.x + hx.y*q0.y + hx.z*q0.z + hx.w*q0.w;
      af += hx.x*q1.x + hx.y*q1.y + hx.z*q1.z + hx.w*q1.w;
      ag += hx.x*q2.x + hx.y*q2.y + hx.z*q2.z + hx.w*q2.w;
      ao += hx.x*q3.x + hx.y*q3.y + hx.z*q3.z + hx.w*q3.w;
    }
    size_t tb = (size_t)t*Bq + b;
    ai += embz[tb*2048 + colj];
    af += embz[tb*2048 + 512 + colj];
    ag += embz[tb*2048 + 1024 + colj];
    ao += embz[tb*2048 + 1536 + colj];
    float co = c_src[b*512 + colj];
    float cn = sigmoidf_(af)*co + sigmoidf_(ai)*tanhf(ag);
    float hn = sigmoidf_(ao)*tanhf(cn);
    c_dst[b*512+colj] = cn;
    hc_ws[((size_t)t*Bq + b)*1024 + colj] = hn;
  }
}

// ---- per-step dec_feat: df = [h;c] @ W_attn (via WaT). 32 blocks x 512 ----
__global__ __launch_bounds__(512) void kC(const float* __restrict__ h_t,
  const float* __restrict__ c_new, const float* __restrict__ WaT_,
  float* __restrict__ df){
  __shared__ float A2[32][1028];
  const int tid = threadIdx.x;
  for (int idx = tid; idx < 32*512; idx += 512){
    int b = idx>>9, k = idx&511;
    A2[b][k]     = h_t[(size_t)b*1024 + k];
    A2[b][512+k] = c_new[b*512+k];
  }
  __syncthreads();
  const int i = blockIdx.x*16 + (tid>>5);
  const int b = tid&31;
  const float* w = WaT_ + (size_t)i*1024;
  float acc=0.f;
  for (int k=0;k<1024;k+=4){
    float4 a = *(const float4*)&A2[b][k];
    float4 q = *(const float4*)(w+k);
    acc += a.x*q.x + a.y*q.y + a.z*q.z + a.w*q.w;
  }
  df[b*512+i] = acc;
}

// ---- per-step attention partials. 256 blocks (b, s-chunk of 64) x 512 ----
__global__ __launch_bounds__(512) void kD(const float* __restrict__ EF,
  const float* __restrict__ df, const float* __restrict__ cov,
  const float* __restrict__ vvec, const float* __restrict__ wcov,
  const float* __restrict__ bcov, const float* __restrict__ mask,
  float* __restrict__ cp, float* __restrict__ mZ, float* __restrict__ e_rows, int t)
{
  __shared__ float dfl[512], vl[512], wcl[512], bcl[512];
  __shared__ float el[64], wl[64];
  __shared__ float mlsh;
  const int tid = threadIdx.x;
  const int b = blockIdx.x >> 3, sc = blockIdx.x & 7;
  const int s0 = sc*64;
  dfl[tid] = df[b*512+tid];
  vl[tid]  = vvec[tid];
  wcl[tid] = wcov[tid];
  bcl[tid] = bcov[tid];
  __syncthreads();
  const int wv = tid>>6, lane = tid&63;
  const int j0 = lane*8;
  float dd[8], vv[8], wc[8], bc[8];
  *(float4*)&dd[0] = *(const float4*)&dfl[j0]; *(float4*)&dd[4] = *(const float4*)&dfl[j0+4];
  *(float4*)&vv[0] = *(const float4*)&vl[j0];  *(float4*)&vv[4] = *(const float4*)&vl[j0+4];
  *(float4*)&wc[0] = *(const float4*)&wcl[j0]; *(float4*)&wc[4] = *(const float4*)&wcl[j0+4];
  *(float4*)&bc[0] = *(const float4*)&bcl[j0]; *(float4*)&bc[4] = *(const float4*)&bcl[j0+4];
  for (int r=0;r<8;++r){
    const int s = wv*8 + r;
    const float* efr = EF + ((size_t)(b*512 + s0 + s))*512;
    float ef[8];
    *(float4*)&ef[0] = *(const float4*)(efr + j0);
    *(float4*)&ef[4] = *(const float4*)(efr + j0 + 4);
    float acc = 0.f;
    if (t>0){
      float cvs = cov[b*512 + s0 + s];
      #pragma unroll
      for (int q=0;q<8;++q) acc += vv[q]*tanhf(ef[q] + dd[q] + cvs*wc[q] + bc[q]);
    } else {
      #pragma unroll
      for (int q=0;q<8;++q) acc += vv[q]*tanhf(ef[q] + dd[q]);
    }
    #pragma unroll
    for (int off=32; off>0; off>>=1) acc += __shfl_down(acc, off);
    if (lane==0) el[s] = acc;
  }
  __syncthreads();
  if (tid < 64){
    float m = el[tid];
    #pragma unroll
    for (int off=32; off>0; off>>=1) m = fmaxf(m, __shfl_xor(m, off));
    if (tid==0) mlsh = m;
  }
  __syncthreads();
  const float ml = mlsh;
  if (tid < 64){
    float w = mask[b*512+s0+tid]*__expf(el[tid]-ml);
    wl[tid] = w;
    float z = w;
    #pragma unroll
    for (int off=32; off>0; off>>=1) z += __shfl_xor(z, off);
    if (tid==0){ mZ[(b*8+sc)*2] = ml; mZ[(b*8+sc)*2+1] = z; }
    e_rows[b*512+s0+tid] = el[tid];
  }
  __syncthreads();
  float cpv = 0.f;
  const float* efc = EF + ((size_t)(b*512 + s0))*512 + tid;
  for (int s=0;s<64;++s) cpv += wl[s]*efc[(size_t)s*512];
  cp[((size_t)(b*8+sc))*512 + tid] = cpv;
}

// ---- OUTm = [h,ctx] @ W_out ----
__global__ __launch_bounds__(512) void k_mid(const float* __restrict__ hc,
    const float* __restrict__ W_out, float* __restrict__ outm){
  __shared__ float A[16][256];
  const int tid=threadIdx.x;
  const int r0=blockIdx.x*16;
  float acc[16];
  #pragma unroll
  for (int r=0;r<16;++r) acc[r]=0.f;
  for (int kc=0;kc<4;++kc){
    __syncthreads();
    for (int i=tid;i<16*256;i+=512){
      int rr=i>>8, kk=i&255;
      A[rr][kk]=hc[(size_t)(r0+rr)*1024 + kc*256+kk];
    }
    __syncthreads();
    for (int k=0;k<256;++k){
      float w=W_out[(size_t)(kc*256+k)*HIDq + tid];
      #pragma unroll
      for (int r=0;r<16;++r) acc[r]+=A[r][k]*w;
    }
  }
  #pragma unroll
  for (int r=0;r<16;++r) outm[(size_t)(r0+r)*HIDq+tid]=acc[r];
}

// ---- logits = OUTm @ W_proj + b_proj -> d_out rows ----
__global__ __launch_bounds__(512) void k_proj(const float* __restrict__ outm,
    const float* __restrict__ W_proj, const float* __restrict__ b_proj,
    float* __restrict__ out){
  __shared__ float A[64][128];
  const int tid = threadIdx.x;
  const int r0  = blockIdx.y * 64;
  const int n   = blockIdx.x * 512 + tid;
  const bool ok = (n < VOCABq);
  float acc[64];
  #pragma unroll
  for (int r=0;r<64;++r) acc[r]=0.f;
  for (int kc=0;kc<4;++kc){
    __syncthreads();
    for (int i=tid;i<64*128;i+=512){
      int rr=i>>7, kk=i&127;
      A[rr][kk]=outm[(size_t)(r0+rr)*HIDq + kc*128 + kk];
    }
    __syncthreads();
    if (ok){
      const float* wp = W_proj + (size_t)(kc*128)*VOCABq + n;
      for (int k=0;k<128;++k){
        float w = wp[(size_t)k*VOCABq];
        #pragma unroll
        for (int r=0;r<64;++r) acc[r] += A[r][k]*w;
      }
    }
  }
  if (ok){
    float bp = b_proj[n];
    #pragma unroll
    for (int r=0;r<64;++r) out[(size_t)(r0+r)*VEXTq + n] = acc[r]+bp;
  }
}

// ---- per-row softmax * p_gen, zero OOV, scatter-add (1-pg)*attn ----
__global__ __launch_bounds__(256) void k_sm(float* __restrict__ out,
    const float* __restrict__ pgen, const float* __restrict__ attn_ws,
    const int* __restrict__ enc_ids){
  __shared__ float redm[4], reds[4];
  const int row=blockIdx.x, tid=threadIdx.x;
  const int b = row & (Bq-1);
  float* orow = out + (size_t)row*VEXTq;
  float m=-1e30f, s=0.f;
  for (int i=tid;i<VOCABq;i+=256){
    float l=orow[i];
    float nm=fmaxf(m,l);
    s = s*__expf(m-nm) + __expf(l-nm);
    m = nm;
  }
  #pragma unroll
  for (int off=32; off>0; off>>=1){
    float om=__shfl_down(m,off), os=__shfl_down(s,off);
    float nm=fmaxf(m,om);
    s = s*__expf(m-nm)+os*__expf(om-nm);
    m = nm;
  }
  int lane=tid&63, wid=tid>>6;
  if (lane==0){ redm[wid]=m; reds[wid]=s; }
  __syncthreads();
  float M=redm[0];
  #pragma unroll
  for (int w=1;w<4;++w) M=fmaxf(M,redm[w]);
  float Ssum=0.f;
  #pragma unroll
  for (int w=0;w<4;++w) Ssum += reds[w]*__expf(redm[w]-M);
  const float pg = pgen[row];
  const float scale = pg/Ssum;
  for (int i=tid;i<VOCABq;i+=256) orow[i]=scale*__expf(orow[i]-M);
  for (int i=VOCABq+tid;i<VEXTq;i+=256) orow[i]=0.f;
  __syncthreads();
  const float w1 = 1.f-pg;
  const float* arow = attn_ws + (size_t)row*Sq;
  const int* ids = enc_ids + b*Sq;
  for (int si=tid; si<Sq; si+=256)
    atomicAdd(&orow[ids[si]], w1*arow[si]);
}

extern "C" void kernel_launch(void* const* d_in, const int* in_sizes, int n_in,
                              void* d_out, int out_size, void* d_ws, size_t ws_size,
                              hipStream_t stream) {
  (void)in_sizes; (void)n_in; (void)out_size; (void)ws_size;
  const int*   dec_ids    = (const int*)  d_in[0];
  const int*   enc_ids    = (const int*)  d_in[1];
  const float* enc_states = (const float*)d_in[2];
  const float* mask       = (const float*)d_in[3];
  const float* init_h     = (const float*)d_in[4];
  const float* init_c     = (const float*)d_in[5];
  const float* embeddings = (const float*)d_in[6];
  const float* W_enc      = (const float*)d_in[7];
  const float* b_enc      = (const float*)d_in[8];
  const float* W_attn     = (const float*)d_in[9];
  const float* vvec       = (const float*)d_in[10];
  const float* w_cov      = (const float*)d_in[11];
  const float* b_cov      = (const float*)d_in[12];
  const float* W_x        = (const float*)d_in[13];
  const float* W_out      = (const float*)d_in[14];
  const float* Wk         = (const float*)d_in[15];
  const float* Wr         = (const float*)d_in[16];
  const float* b_lstm     = (const float*)d_in[17];
  const float* W_pgen     = (const float*)d_in[18];
  const float* W_proj     = (const float*)d_in[19];
  const float* b_proj     = (const float*)d_in[20];
  float* out = (float*)d_out;
  float* ws  = (float*)d_ws;

  float* EF      = ws;                              // 8,388,608
  float* attn_ws = EF      + (size_t)8388608;       //   524,288
  float* hc_ws   = attn_ws + (size_t)524288;        // 1,048,576
  float* outm    = hc_ws   + (size_t)1048576;       //   524,288
  float* pgen_ws = outm    + (size_t)524288;        //     1,024
  float* embx    = pgen_ws + (size_t)1024;          //   524,288
  float* embxp   = embx    + (size_t)524288;        //     1,024
  float* embz    = embxp   + (size_t)1024;          // 2,097,152
  float* WXKT_   = embz    + (size_t)2097152;       // 1,048,576
  float* WrT_    = WXKT_   + (size_t)1048576;       // 1,048,576
  float* WaT_    = WrT_    + (size_t)1048576;       //   524,288
  float* Wp1p    = WaT_    + (size_t)524288;        //       512
  float* cp      = Wp1p    + (size_t)512;           //   131,072
  float* mZ      = cp      + (size_t)131072;        //       512
  float* e_rows  = mZ      + (size_t)512;           //    16,384
  float* df      = e_rows  + (size_t)16384;         //    16,384
  float* cov     = df      + (size_t)16384;         //    16,384
  float* c_bufs  = cov     + (size_t)16384;         //    32,768

  // ---- precompute ----
  k_enc<<<(Bq*Sq)/16, 512, 0, stream>>>(enc_states, W_enc, b_enc, EF);
  k_embx<<<64, 512, 0, stream>>>(dec_ids, embeddings, W_x, W_pgen, embx, embxp);
  {
    dim3 g(64,4);
    k_embz<<<g, 512, 0, stream>>>(embx, Wk, b_lstm, embz);
  }
  {
    dim3 g(32,16);
    k_wxk<<<g, 512, 0, stream>>>(Wk, W_x, WXKT_);
  }
  {
    dim3 g(64,16);   // WrT: in [512][2048] -> out [2048][512]
    k_trans<<<g, 512, 0, stream>>>(Wr, WrT_, 512, 2048);
  }
  {
    dim3 g(16,32);   // WaT: in [1024][512] -> out [512][1024]
    k_trans<<<g, 512, 0, stream>>>(W_attn, WaT_, 1024, 512);
  }
  k_wp<<<1, 512, 0, stream>>>(W_x, W_pgen, Wp1p);
  hipMemcpyAsync(c_bufs, init_c, (size_t)Bq*HIDq*sizeof(float),
                 hipMemcpyDeviceToDevice, stream);

  // ---- recurrence ----
  for (int t=0; t<Tq; ++t){
    const int rb = t & 1, wb = 1 - rb;
    const float* h_src = (t==0) ? init_h : (hc_ws + (size_t)(t-1)*Bq*1024);
    const int h_stride = (t==0) ? 512 : 1024;
    kB<<<32, 512, 0, stream>>>(h_src, h_stride,
        c_bufs + (size_t)rb*Bq*HIDq, c_bufs + (size_t)wb*Bq*HIDq,
        WXKT_, WrT_, embz, embxp, Wp1p, W_pgen,
        cp, mZ, e_rows, mask, hc_ws, attn_ws, cov, pgen_ws, t, 1);
    kC<<<32, 512, 0, stream>>>(hc_ws + (size_t)t*Bq*1024,
        c_bufs + (size_t)wb*Bq*HIDq, WaT_, df);
    kD<<<256, 512, 0, stream>>>(EF, df, cov, vvec, w_cov, b_cov, mask,
        cp, mZ, e_rows, t);
  }
  // finalize step T-1 outputs (ctx, attn, pgen)
  kB<<<32, 512, 0, stream>>>(hc_ws + (size_t)(Tq-1)*Bq*1024, 1024,
      c_bufs + (size_t)(Tq&1)*Bq*HIDq, c_bufs + (size_t)(1-(Tq&1))*Bq*HIDq,
      WXKT_, WrT_, embz, embxp, Wp1p, W_pgen,
      cp, mZ, e_rows, mask, hc_ws, attn_ws, cov, pgen_ws, Tq, 0);

  // ---- output projection + softmax + scatter ----
  k_mid<<<(Tq*Bq)/16, 512, 0, stream>>>(hc_ws, W_out, outm);
  {
    dim3 gp(98, 16);
    k_proj<<<gp, 512, 0, stream>>>(outm, W_proj, b_proj, out);
  }
  k_sm<<<Tq*Bq, 256, 0, stream>>>(out, pgen_ws, attn_ws, enc_ids);
}

// Round 3
// 4631.065 us; speedup vs baseline: 2.5201x; 1.5326x over previous
//
#include <hip/hip_runtime.h>
#include <math.h>

#define Bq 32
#define Sq 512
#define Tq 32
#define EMBq 256
#define HIDq 512
#define VOCABq 50000
#define OOVq 100
#define VEXTq (VOCABq + OOVq)
#define HALF_N 25088   /* padded half of vocab for WT buffer (196*128) */

typedef unsigned short u16;
typedef __attribute__((ext_vector_type(8))) short bf16x8;
typedef __attribute__((ext_vector_type(4))) float f32x4;

__device__ __forceinline__ float sigmoidf_(float x){ return 1.0f/(1.0f+__expf(-x)); }

__device__ __forceinline__ u16 f2bf(float x){
  union{float f; unsigned u;} v; v.f=x;
  unsigned r = v.u + 0x7FFFu + ((v.u>>16)&1u);
  return (u16)(r>>16);
}

__device__ __forceinline__ float blockSum512(float v, float* red){
  #pragma unroll
  for (int off=32; off>0; off>>=1) v += __shfl_down(v, off);
  int lane = threadIdx.x & 63, wid = threadIdx.x >> 6;
  __syncthreads();
  if (lane==0) red[wid]=v;
  __syncthreads();
  float t=0.f;
  #pragma unroll
  for (int w=0;w<8;++w) t+=red[w];
  return t;
}

// ---- enc_feat = encoder_states @ W_enc + b_enc ----
__global__ __launch_bounds__(512) void k_enc(const float* __restrict__ es,
    const float* __restrict__ W_enc, const float* __restrict__ b_enc,
    float* __restrict__ ef){
  __shared__ float A[16][256];
  const int tid = threadIdx.x;
  const int r0  = blockIdx.x * 16;
  float acc[16];
  #pragma unroll
  for (int r=0;r<16;++r) acc[r]=0.f;
  for (int kc=0;kc<2;++kc){
    __syncthreads();
    for (int i=tid;i<16*256;i+=512){
      int rr=i>>8, kk=i&255;
      A[rr][kk]=es[(size_t)(r0+rr)*HIDq + kc*256 + kk];
    }
    __syncthreads();
    for (int k=0;k<256;++k){
      float w=W_enc[(size_t)(kc*256+k)*HIDq + tid];
      #pragma unroll
      for (int r=0;r<16;++r) acc[r]+=A[r][k]*w;
    }
  }
  float bb=b_enc[tid];
  #pragma unroll
  for (int r=0;r<16;++r) ef[(size_t)(r0+r)*HIDq+tid]=acc[r]+bb;
}

// ---- embx[t*32+b,:] = emb(dec_ids[b,t]) @ W_x[0:256,:]; embxp = embx . Wp4 ----
__global__ __launch_bounds__(512) void k_embx(const int* __restrict__ dec_ids,
  const float* __restrict__ emb, const float* __restrict__ W_x,
  const float* __restrict__ Wpgen, float* __restrict__ embx, float* __restrict__ embxp){
  __shared__ float A[16][257];
  __shared__ int ids[16];
  __shared__ float red[8];
  const int tid = threadIdx.x, r0 = blockIdx.x*16;
  if (tid<16){
    int row = r0+tid, tt = row>>5, bb = row&31;
    ids[tid] = dec_ids[bb*Tq + tt];
  }
  __syncthreads();
  for (int idx=tid; idx<16*256; idx+=512){
    int rr = idx>>8, kk = idx&255;
    A[rr][kk] = emb[(size_t)ids[rr]*EMBq + kk];
  }
  __syncthreads();
  float acc[16];
  #pragma unroll
  for (int r=0;r<16;++r) acc[r]=0.f;
  for (int k=0;k<256;++k){
    float w = W_x[(size_t)k*HIDq + tid];
    #pragma unroll
    for (int r=0;r<16;++r) acc[r] += A[r][k]*w;
  }
  float wp4 = Wpgen[1536+tid];
  for (int r=0;r<16;++r){
    embx[(size_t)(r0+r)*HIDq + tid] = acc[r];
    float s = blockSum512(acc[r]*wp4, red);
    if (tid==0) embxp[r0+r] = s;
  }
}

// ---- embz = embx @ Wk + b_lstm   [1024,512]x[512,2048] ----
__global__ __launch_bounds__(512) void k_embz(const float* __restrict__ embx,
  const float* __restrict__ Wk, const float* __restrict__ b_lstm, float* __restrict__ embz){
  __shared__ float A[16][513];
  const int tid = threadIdx.x;
  const int r0 = blockIdx.x*16;
  const int n  = blockIdx.y*512 + tid;
  for (int idx=tid; idx<16*512; idx+=512){
    int rr=idx>>9, kk=idx&511;
    A[rr][kk] = embx[(size_t)(r0+rr)*HIDq + kk];
  }
  __syncthreads();
  float acc[16];
  #pragma unroll
  for (int r=0;r<16;++r) acc[r]=0.f;
  for (int k=0;k<512;++k){
    float w = Wk[(size_t)k*2048 + n];
    #pragma unroll
    for (int r=0;r<16;++r) acc[r] += A[r][k]*w;
  }
  float bl = b_lstm[n];
  #pragma unroll
  for (int r=0;r<16;++r) embz[(size_t)(r0+r)*2048 + n] = acc[r]+bl;
}

// ---- WXKT[n][j] = sum_i Wk[i][n] * W_x[256+j][i] ----
__global__ __launch_bounds__(512) void k_wxk(const float* __restrict__ Wk,
    const float* __restrict__ W_x, float* __restrict__ WXKT_){
  __shared__ float KT[32][64];
  __shared__ float X2[32][33];
  const int tid = threadIdx.x;
  const int n0 = blockIdx.x * 64;
  const int j0 = blockIdx.y * 32;
  const int jj = tid & 31;
  const int ng = tid >> 5;   // 0..15
  float acc[4] = {0,0,0,0};
  for (int i0=0;i0<512;i0+=32){
    __syncthreads();
    for (int idx=tid; idx<32*64; idx+=512){
      int ii = idx>>6, nn = idx&63;
      KT[ii][nn] = Wk[(size_t)(i0+ii)*2048 + n0+nn];
    }
    for (int idx=tid; idx<32*32; idx+=512){
      int j2 = idx>>5, i2 = idx&31;
      X2[j2][i2] = W_x[(size_t)(256+j0+j2)*HIDq + i0+i2];
    }
    __syncthreads();
    for (int ii=0;ii<32;++ii){
      float xv = X2[jj][ii];
      #pragma unroll
      for (int q=0;q<4;++q) acc[q] += KT[ii][ng*4+q]*xv;
    }
  }
  #pragma unroll
  for (int q=0;q<4;++q) WXKT_[(size_t)(n0+ng*4+q)*512 + j0+jj] = acc[q];
}

// ---- generic 32x32 tiled transpose: out[n][k] = in[k][n], in is [K][N] ----
__global__ __launch_bounds__(512) void k_trans(const float* __restrict__ in,
    float* __restrict__ out, int K, int N){
  __shared__ float T[32][33];
  const int n0 = blockIdx.x*32, k0 = blockIdx.y*32;
  const int tid = threadIdx.x;
  for (int idx=tid; idx<1024; idx+=512){
    int kk = idx>>5, nn = idx&31;
    T[kk][nn] = in[(size_t)(k0+kk)*N + n0+nn];
  }
  __syncthreads();
  for (int idx=tid; idx<1024; idx+=512){
    int nn = idx>>5, kk = idx&31;
    out[(size_t)(n0+nn)*K + k0+kk] = T[kk][nn];
  }
}

// ---- Wp1p[j] = W_pgen[j] + sum_i W_x[256+j][i]*W_pgen[1536+i] ----
__global__ __launch_bounds__(512) void k_wp(const float* __restrict__ W_x,
  const float* __restrict__ Wpgen, float* __restrict__ Wp1p){
  int j = threadIdx.x;
  const float* row = W_x + (size_t)(256+j)*HIDq;
  float s=0.f;
  for (int i=0;i<512;++i) s += row[i]*Wpgen[1536+i];
  Wp1p[j] = Wpgen[j] + s;
}

// ---- per-step LSTM kernel: finalize ctx(t-1) + z + gates. 32 blocks x 512 ----
__global__ __launch_bounds__(512) void kB(
  const float* __restrict__ h_src, int h_stride,
  const float* __restrict__ c_src, float* __restrict__ c_dst,
  const float* __restrict__ WXKT_, const float* __restrict__ WrT_,
  const float* __restrict__ embz, const float* __restrict__ embxp,
  const float* __restrict__ Wp1p, const float* __restrict__ Wpgen,
  const float* __restrict__ cp, const float* __restrict__ mZ,
  const float* __restrict__ e_rows, const float* __restrict__ mask,
  float* __restrict__ hc_ws, float* __restrict__ attn_ws,
  float* __restrict__ cov, float* __restrict__ pgen_ws,
  int t, int doMain)
{
  __shared__ float Actx[32][516];
  __shared__ float Ah[32][516];
  __shared__ float Mb[32], Db[32], Wl[32][8];
  __shared__ float red[8];
  const int tid = threadIdx.x, bid = blockIdx.x;

  for (int idx = tid; idx < 32*512; idx += 512){
    int b = idx >> 9, k = idx & 511;
    Ah[b][k] = h_src[(size_t)b*h_stride + k];
  }
  if (t == 0){
    for (int idx = tid; idx < 32*512; idx += 512){
      int b=idx>>9,k=idx&511; Actx[b][k]=0.f;
    }
    __syncthreads();
  } else {
    if (tid < 32){
      int b = tid;
      float m = mZ[(b*8+0)*2];
      #pragma unroll
      for (int l=1;l<8;++l) m = fmaxf(m, mZ[(b*8+l)*2]);
      float den = 0.f;
      #pragma unroll
      for (int l=0;l<8;++l){
        float w = __expf(mZ[(b*8+l)*2] - m);
        Wl[b][l] = w;
        den += w * mZ[(b*8+l)*2+1];
      }
      Mb[b] = m; Db[b] = den;
    }
    __syncthreads();
    for (int b=0;b<32;++b){
      float s = 0.f;
      #pragma unroll
      for (int l=0;l<8;++l) s += cp[((size_t)(b*8+l))*512 + tid] * Wl[b][l];
      Actx[b][tid] = s / Db[b];
    }
    __syncthreads();
    {
      const int b = bid;
      const float M = Mb[b], den = Db[b];
      float a = mask[b*512+tid] * __expf(e_rows[b*512+tid] - M) / den;
      attn_ws[((size_t)(t-1)*Bq + b)*Sq + tid] = a;
      cov[b*512+tid] = (t==1) ? a : (cov[b*512+tid] + a);
      hc_ws[((size_t)(t-1)*Bq + b)*1024 + 512 + tid] = Actx[b][tid];
      float val = Actx[b][tid]*Wp1p[tid] + Ah[b][tid]*Wpgen[512+tid]
                + c_src[b*512+tid]*Wpgen[1024+tid];
      float tot = blockSum512(val, red);
      if (tid==0) pgen_ws[(t-1)*Bq + b] = sigmoidf_(tot + embxp[(t-1)*Bq + b]);
    }
    __syncthreads();
  }

  if (doMain){
    const int j = tid >> 5;
    const int b = tid & 31;
    const int colj = bid*16 + j;
    const float* w0 = WXKT_ + (size_t)colj*512;
    const float* w1 = WXKT_ + (size_t)(512+colj)*512;
    const float* w2 = WXKT_ + (size_t)(1024+colj)*512;
    const float* w3 = WXKT_ + (size_t)(1536+colj)*512;
    float ai=0.f, af=0.f, ag=0.f, ao=0.f;
    for (int k=0;k<512;k+=4){
      float4 cx = *(const float4*)&Actx[b][k];
      float4 q0 = *(const float4*)(w0+k);
      float4 q1 = *(const float4*)(w1+k);
      float4 q2 = *(const float4*)(w2+k);
      float4 q3 = *(const float4*)(w3+k);
      ai += cx.x*q0.x + cx.y*q0.y + cx.z*q0.z + cx.w*q0.w;
      af += cx.x*q1.x + cx.y*q1.y + cx.z*q1.z + cx.w*q1.w;
      ag += cx.x*q2.x + cx.y*q2.y + cx.z*q2.z + cx.w*q2.w;
      ao += cx.x*q3.x + cx.y*q3.y + cx.z*q3.z + cx.w*q3.w;
    }
    const float* r0p = WrT_ + (size_t)colj*512;
    const float* r1p = WrT_ + (size_t)(512+colj)*512;
    const float* r2p = WrT_ + (size_t)(1024+colj)*512;
    const float* r3p = WrT_ + (size_t)(1536+colj)*512;
    for (int k=0;k<512;k+=4){
      float4 hx = *(const float4*)&Ah[b][k];
      float4 q0 = *(const float4*)(r0p+k);
      float4 q1 = *(const float4*)(r1p+k);
      float4 q2 = *(const float4*)(r2p+k);
      float4 q3 = *(const float4*)(r3p+k);
      ai += hx.x*q0.x + hx.y*q0.y + hx.z*q0.z + hx.w*q0.w;
      af += hx.x*q1.x + hx.y*q1.y + hx.z*q1.z + hx.w*q1.w;
      ag += hx.x*q2.x + hx.y*q2.y + hx.z*q2.z + hx.w*q2.w;
      ao += hx.x*q3.x + hx.y*q3.y + hx.z*q3.z + hx.w*q3.w;
    }
    size_t tb = (size_t)t*Bq + b;
    ai += embz[tb*2048 + colj];
    af += embz[tb*2048 + 512 + colj];
    ag += embz[tb*2048 + 1024 + colj];
    ao += embz[tb*2048 + 1536 + colj];
    float co = c_src[b*512 + colj];
    float cn = sigmoidf_(af)*co + sigmoidf_(ai)*tanhf(ag);
    float hn = sigmoidf_(ao)*tanhf(cn);
    c_dst[b*512+colj] = cn;
    hc_ws[((size_t)t*Bq + b)*1024 + colj] = hn;
  }
}

// ---- per-step dec_feat: df = [h;c] @ W_attn (via WaT). 32 blocks x 512 ----
__global__ __launch_bounds__(512) void kC(const float* __restrict__ h_t,
  const float* __restrict__ c_new, const float* __restrict__ WaT_,
  float* __restrict__ df){
  __shared__ float A2[32][1028];
  const int tid = threadIdx.x;
  for (int idx = tid; idx < 32*512; idx += 512){
    int b = idx>>9, k = idx&511;
    A2[b][k]     = h_t[(size_t)b*1024 + k];
    A2[b][512+k] = c_new[b*512+k];
  }
  __syncthreads();
  const int i = blockIdx.x*16 + (tid>>5);
  const int b = tid&31;
  const float* w = WaT_ + (size_t)i*1024;
  float acc=0.f;
  for (int k=0;k<1024;k+=4){
    float4 a = *(const float4*)&A2[b][k];
    float4 q = *(const float4*)(w+k);
    acc += a.x*q.x + a.y*q.y + a.z*q.z + a.w*q.w;
  }
  df[b*512+i] = acc;
}

// ---- per-step attention partials. 256 blocks (b, s-chunk of 64) x 512 ----
__global__ __launch_bounds__(512) void kD(const float* __restrict__ EF,
  const float* __restrict__ df, const float* __restrict__ cov,
  const float* __restrict__ vvec, const float* __restrict__ wcov,
  const float* __restrict__ bcov, const float* __restrict__ mask,
  float* __restrict__ cp, float* __restrict__ mZ, float* __restrict__ e_rows, int t)
{
  __shared__ float dfl[512], vl[512], wcl[512], bcl[512];
  __shared__ float el[64], wl[64];
  __shared__ float mlsh;
  const int tid = threadIdx.x;
  const int b = blockIdx.x >> 3, sc = blockIdx.x & 7;
  const int s0 = sc*64;
  dfl[tid] = df[b*512+tid];
  vl[tid]  = vvec[tid];
  wcl[tid] = wcov[tid];
  bcl[tid] = bcov[tid];
  __syncthreads();
  const int wv = tid>>6, lane = tid&63;
  const int j0 = lane*8;
  float dd[8], vv[8], wc[8], bc[8];
  *(float4*)&dd[0] = *(const float4*)&dfl[j0]; *(float4*)&dd[4] = *(const float4*)&dfl[j0+4];
  *(float4*)&vv[0] = *(const float4*)&vl[j0];  *(float4*)&vv[4] = *(const float4*)&vl[j0+4];
  *(float4*)&wc[0] = *(const float4*)&wcl[j0]; *(float4*)&wc[4] = *(const float4*)&wcl[j0+4];
  *(float4*)&bc[0] = *(const float4*)&bcl[j0]; *(float4*)&bc[4] = *(const float4*)&bcl[j0+4];
  for (int r=0;r<8;++r){
    const int s = wv*8 + r;
    const float* efr = EF + ((size_t)(b*512 + s0 + s))*512;
    float ef[8];
    *(float4*)&ef[0] = *(const float4*)(efr + j0);
    *(float4*)&ef[4] = *(const float4*)(efr + j0 + 4);
    float acc = 0.f;
    if (t>0){
      float cvs = cov[b*512 + s0 + s];
      #pragma unroll
      for (int q=0;q<8;++q) acc += vv[q]*tanhf(ef[q] + dd[q] + cvs*wc[q] + bc[q]);
    } else {
      #pragma unroll
      for (int q=0;q<8;++q) acc += vv[q]*tanhf(ef[q] + dd[q]);
    }
    #pragma unroll
    for (int off=32; off>0; off>>=1) acc += __shfl_down(acc, off);
    if (lane==0) el[s] = acc;
  }
  __syncthreads();
  if (tid < 64){
    float m = el[tid];
    #pragma unroll
    for (int off=32; off>0; off>>=1) m = fmaxf(m, __shfl_xor(m, off));
    if (tid==0) mlsh = m;
  }
  __syncthreads();
  const float ml = mlsh;
  if (tid < 64){
    float w = mask[b*512+s0+tid]*__expf(el[tid]-ml);
    wl[tid] = w;
    float z = w;
    #pragma unroll
    for (int off=32; off>0; off>>=1) z += __shfl_xor(z, off);
    if (tid==0){ mZ[(b*8+sc)*2] = ml; mZ[(b*8+sc)*2+1] = z; }
    e_rows[b*512+s0+tid] = el[tid];
  }
  __syncthreads();
  float cpv = 0.f;
  const float* efc = EF + ((size_t)(b*512 + s0))*512 + tid;
  for (int s=0;s<64;++s) cpv += wl[s]*efc[(size_t)s*512];
  cp[((size_t)(b*8+sc))*512 + tid] = cpv;
}

// ---- OUTm = [h,ctx] @ W_out  -> bf16 ----
__global__ __launch_bounds__(512) void k_mid(const float* __restrict__ hc,
    const float* __restrict__ W_out, u16* __restrict__ outm_bf){
  __shared__ float A[16][256];
  const int tid=threadIdx.x;
  const int r0=blockIdx.x*16;
  float acc[16];
  #pragma unroll
  for (int r=0;r<16;++r) acc[r]=0.f;
  for (int kc=0;kc<4;++kc){
    __syncthreads();
    for (int i=tid;i<16*256;i+=512){
      int rr=i>>8, kk=i&255;
      A[rr][kk]=hc[(size_t)(r0+rr)*1024 + kc*256+kk];
    }
    __syncthreads();
    for (int k=0;k<256;++k){
      float w=W_out[(size_t)(kc*256+k)*HIDq + tid];
      #pragma unroll
      for (int r=0;r<16;++r) acc[r]+=A[r][k]*w;
    }
  }
  #pragma unroll
  for (int r=0;r<16;++r) outm_bf[(size_t)(r0+r)*HIDq+tid]=f2bf(acc[r]);
}

// ---- W_proj f32 [512][50000] -> WT bf16 [HALF_N][512] (transposed half) ----
__global__ __launch_bounds__(256) void k_wcvt(const float* __restrict__ Wp,
    u16* __restrict__ WT, int n_base){
  __shared__ float T[32][33];
  const int n0 = blockIdx.x*32, k0 = blockIdx.y*32;
  const int tid = threadIdx.x;
  #pragma unroll
  for (int it=0; it<4; ++it){
    int id = tid + it*256;
    int kk = id>>5, nn = id&31;
    int gn = n_base + n0 + nn;
    T[kk][nn] = (gn < VOCABq) ? Wp[(size_t)(k0+kk)*VOCABq + gn] : 0.f;
  }
  __syncthreads();
  #pragma unroll
  for (int it=0; it<4; ++it){
    int id = tid + it*256;
    int nn = id>>5, kk = id&31;
    WT[(size_t)(n0+nn)*512 + k0+kk] = f2bf(T[kk][nn]);
  }
}

// ---- logits = Abf[1024,512] @ WT^T + b_proj -> d_out (f32), MFMA bf16 ----
// grid (8, 196): x = m-tile (fast; shares B tile in L2), y = n-tile within half
__global__ __launch_bounds__(256) void k_projm(const u16* __restrict__ Abf,
    const u16* __restrict__ WT, const float* __restrict__ b_proj,
    float* __restrict__ out, int n_base){
  __shared__ u16 As[128*40];
  __shared__ u16 Bs[128*40];
  const int tid = threadIdx.x;
  const int m0 = blockIdx.x * 128;
  const int n0 = blockIdx.y * 128;
  const int wid = tid>>6, lane = tid&63;
  const int wm = (wid>>1)*64, wn = (wid&1)*64;
  const int l15 = lane&15, l4 = lane>>4;
  f32x4 acc[4][4];
  #pragma unroll
  for (int mi=0;mi<4;++mi)
    #pragma unroll
    for (int ni=0;ni<4;++ni) acc[mi][ni] = (f32x4){0.f,0.f,0.f,0.f};

  for (int kt=0; kt<16; ++kt){
    const int k0 = kt*32;
    __syncthreads();
    #pragma unroll
    for (int it=0; it<2; ++it){
      int id = tid + it*256;
      int row = id>>2, c4 = id&3;
      uint4 va = *(const uint4*)(Abf + (size_t)(m0+row)*512 + k0 + c4*8);
      *(uint4*)(&As[row*40 + c4*8]) = va;
      uint4 vb = *(const uint4*)(WT + (size_t)(n0+row)*512 + k0 + c4*8);
      *(uint4*)(&Bs[row*40 + c4*8]) = vb;
    }
    __syncthreads();
    bf16x8 a[4], b[4];
    #pragma unroll
    for (int mi=0;mi<4;++mi)
      a[mi] = *(const bf16x8*)(&As[(wm + mi*16 + l15)*40 + l4*8]);
    #pragma unroll
    for (int ni=0;ni<4;++ni)
      b[ni] = *(const bf16x8*)(&Bs[(wn + ni*16 + l15)*40 + l4*8]);
    #pragma unroll
    for (int mi=0;mi<4;++mi)
      #pragma unroll
      for (int ni=0;ni<4;++ni)
        acc[mi][ni] = __builtin_amdgcn_mfma_f32_16x16x32_bf16(a[mi], b[ni], acc[mi][ni], 0,0,0);
  }

  #pragma unroll
  for (int ni=0;ni<4;++ni){
    const int col = n_base + n0 + wn + ni*16 + l15;
    if (col < VOCABq){
      const float bp = b_proj[col];
      #pragma unroll
      for (int mi=0;mi<4;++mi){
        const int rbase = m0 + wm + mi*16 + l4*4;
        #pragma unroll
        for (int r=0;r<4;++r)
          out[(size_t)(rbase+r)*VEXTq + col] = acc[mi][ni][r] + bp;
      }
    }
  }
}

// ---- per-row softmax * p_gen, zero OOV, scatter-add (1-pg)*attn ----
__global__ __launch_bounds__(256) void k_sm(float* __restrict__ out,
    const float* __restrict__ pgen, const float* __restrict__ attn_ws,
    const int* __restrict__ enc_ids){
  __shared__ float redm[4], reds[4];
  const int row=blockIdx.x, tid=threadIdx.x;
  const int b = row & (Bq-1);
  float* orow = out + (size_t)row*VEXTq;
  float m=-1e30f, s=0.f;
  for (int i=tid;i<VOCABq;i+=256){
    float l=orow[i];
    float nm=fmaxf(m,l);
    s = s*__expf(m-nm) + __expf(l-nm);
    m = nm;
  }
  #pragma unroll
  for (int off=32; off>0; off>>=1){
    float om=__shfl_down(m,off), os=__shfl_down(s,off);
    float nm=fmaxf(m,om);
    s = s*__expf(m-nm)+os*__expf(om-nm);
    m = nm;
  }
  int lane=tid&63, wid=tid>>6;
  if (lane==0){ redm[wid]=m; reds[wid]=s; }
  __syncthreads();
  float M=redm[0];
  #pragma unroll
  for (int w=1;w<4;++w) M=fmaxf(M,redm[w]);
  float Ssum=0.f;
  #pragma unroll
  for (int w=0;w<4;++w) Ssum += reds[w]*__expf(redm[w]-M);
  const float pg = pgen[row];
  const float scale = pg/Ssum;
  for (int i=tid;i<VOCABq;i+=256) orow[i]=scale*__expf(orow[i]-M);
  for (int i=VOCABq+tid;i<VEXTq;i+=256) orow[i]=0.f;
  __syncthreads();
  const float w1 = 1.f-pg;
  const float* arow = attn_ws + (size_t)row*Sq;
  const int* ids = enc_ids + b*Sq;
  for (int si=tid; si<Sq; si+=256)
    atomicAdd(&orow[ids[si]], w1*arow[si]);
}

extern "C" void kernel_launch(void* const* d_in, const int* in_sizes, int n_in,
                              void* d_out, int out_size, void* d_ws, size_t ws_size,
                              hipStream_t stream) {
  (void)in_sizes; (void)n_in; (void)out_size; (void)ws_size;
  const int*   dec_ids    = (const int*)  d_in[0];
  const int*   enc_ids    = (const int*)  d_in[1];
  const float* enc_states = (const float*)d_in[2];
  const float* mask       = (const float*)d_in[3];
  const float* init_h     = (const float*)d_in[4];
  const float* init_c     = (const float*)d_in[5];
  const float* embeddings = (const float*)d_in[6];
  const float* W_enc      = (const float*)d_in[7];
  const float* b_enc      = (const float*)d_in[8];
  const float* W_attn     = (const float*)d_in[9];
  const float* vvec       = (const float*)d_in[10];
  const float* w_cov      = (const float*)d_in[11];
  const float* b_cov      = (const float*)d_in[12];
  const float* W_x        = (const float*)d_in[13];
  const float* W_out      = (const float*)d_in[14];
  const float* Wk         = (const float*)d_in[15];
  const float* Wr         = (const float*)d_in[16];
  const float* b_lstm     = (const float*)d_in[17];
  const float* W_pgen     = (const float*)d_in[18];
  const float* W_proj     = (const float*)d_in[19];
  const float* b_proj     = (const float*)d_in[20];
  float* out = (float*)d_out;
  float* ws  = (float*)d_ws;

  float* EF      = ws;                              // 8,388,608
  float* attn_ws = EF      + (size_t)8388608;       //   524,288
  float* hc_ws   = attn_ws + (size_t)524288;        // 1,048,576
  u16*   outm_bf = (u16*)(hc_ws + (size_t)1048576); //   524,288 u16 = 262,144 f32
  float* pgen_ws = hc_ws   + (size_t)1048576 + 262144;
  float* embx    = pgen_ws + (size_t)1024;          //   524,288
  float* embxp   = embx    + (size_t)524288;        //     1,024
  float* embz    = embxp   + (size_t)1024;          // 2,097,152
  float* WXKT_   = embz    + (size_t)2097152;       // 1,048,576
  float* WrT_    = WXKT_   + (size_t)1048576;       // 1,048,576
  float* WaT_    = WrT_    + (size_t)1048576;       //   524,288
  float* Wp1p    = WaT_    + (size_t)524288;        //       512
  float* cp      = Wp1p    + (size_t)512;           //   131,072
  float* mZ      = cp      + (size_t)131072;        //       512
  float* e_rows  = mZ      + (size_t)512;           //    16,384
  float* df      = e_rows  + (size_t)16384;         //    16,384
  float* cov     = df      + (size_t)16384;         //    16,384
  float* c_bufs  = cov     + (size_t)16384;         //    32,768
  u16*   WT      = (u16*)(c_bufs + (size_t)32768);  // HALF_N*512 u16 = 6,422,528 f32

  // ---- precompute ----
  k_enc<<<(Bq*Sq)/16, 512, 0, stream>>>(enc_states, W_enc, b_enc, EF);
  k_embx<<<64, 512, 0, stream>>>(dec_ids, embeddings, W_x, W_pgen, embx, embxp);
  {
    dim3 g(64,4);
    k_embz<<<g, 512, 0, stream>>>(embx, Wk, b_lstm, embz);
  }
  {
    dim3 g(32,16);
    k_wxk<<<g, 512, 0, stream>>>(Wk, W_x, WXKT_);
  }
  {
    dim3 g(64,16);   // WrT: in [512][2048] -> out [2048][512]
    k_trans<<<g, 512, 0, stream>>>(Wr, WrT_, 512, 2048);
  }
  {
    dim3 g(16,32);   // WaT: in [1024][512] -> out [512][1024]
    k_trans<<<g, 512, 0, stream>>>(W_attn, WaT_, 1024, 512);
  }
  k_wp<<<1, 512, 0, stream>>>(W_x, W_pgen, Wp1p);
  hipMemcpyAsync(c_bufs, init_c, (size_t)Bq*HIDq*sizeof(float),
                 hipMemcpyDeviceToDevice, stream);

  // ---- recurrence ----
  for (int t=0; t<Tq; ++t){
    const int rb = t & 1, wb = 1 - rb;
    const float* h_src = (t==0) ? init_h : (hc_ws + (size_t)(t-1)*Bq*1024);
    const int h_stride = (t==0) ? 512 : 1024;
    kB<<<32, 512, 0, stream>>>(h_src, h_stride,
        c_bufs + (size_t)rb*Bq*HIDq, c_bufs + (size_t)wb*Bq*HIDq,
        WXKT_, WrT_, embz, embxp, Wp1p, W_pgen,
        cp, mZ, e_rows, mask, hc_ws, attn_ws, cov, pgen_ws, t, 1);
    kC<<<32, 512, 0, stream>>>(hc_ws + (size_t)t*Bq*1024,
        c_bufs + (size_t)wb*Bq*HIDq, WaT_, df);
    kD<<<256, 512, 0, stream>>>(EF, df, cov, vvec, w_cov, b_cov, mask,
        cp, mZ, e_rows, t);
  }
  // finalize step T-1 outputs (ctx, attn, pgen)
  kB<<<32, 512, 0, stream>>>(hc_ws + (size_t)(Tq-1)*Bq*1024, 1024,
      c_bufs + (size_t)(Tq&1)*Bq*HIDq, c_bufs + (size_t)(1-(Tq&1))*Bq*HIDq,
      WXKT_, WrT_, embz, embxp, Wp1p, W_pgen,
      cp, mZ, e_rows, mask, hc_ws, attn_ws, cov, pgen_ws, Tq, 0);

  // ---- output projection (bf16 MFMA, two vocab halves) + softmax + scatter ----
  k_mid<<<(Tq*Bq)/16, 512, 0, stream>>>(hc_ws, W_out, outm_bf);
  for (int half=0; half<2; ++half){
    const int n_base = half*HALF_N;
    dim3 gc(HALF_N/32, 16);
    k_wcvt<<<gc, 256, 0, stream>>>(W_proj, WT, n_base);
    dim3 gp(8, HALF_N/128);
    k_projm<<<gp, 256, 0, stream>>>(outm_bf, WT, b_proj, out, n_base);
  }
  k_sm<<<Tq*Bq, 256, 0, stream>>>(out, pgen_ws, attn_ws, enc_ids);
}